// Round 6
// baseline (472.782 us; speedup 1.0000x reference)
//
#include <hip/hip_runtime.h>

#define N_INPUT 256
#define HS 32

// ---- bucket-sort CSR build params ----
#define BKT_SHIFT 7
#define BKT_NODES 128           // nodes per bucket
#define NBUCK_MAX 800           // LDS sizing; runtime nbuck = ceil(N/128) = 782
#define CAP 2560                // per-bucket edge capacity (mean 2048, sigma ~45 -> +11 sigma)
#define EPB 16384               // edges per S1 block (R13: was 2048 -> 21-rec runs
                                // per (block,bucket): single-writer lines, L2 merge)

typedef __attribute__((ext_vector_type(8))) short bf16x8;
typedef __attribute__((ext_vector_type(4))) float f32x4;
typedef __attribute__((ext_vector_type(8))) unsigned short u16x8;

// fp32 -> bf16 bits, round-to-nearest-even
__device__ __forceinline__ unsigned short f2bf(float f) {
    unsigned u = __float_as_uint(f);
    unsigned r = u + 0x7FFFu + ((u >> 16) & 1u);
    return (unsigned short)(r >> 16);
}
__device__ __forceinline__ float bf2f(unsigned short u) {
    return __uint_as_float((unsigned)u << 16);
}

// R12 prep: zero gtail + pack the frag-ordered bf16 weights ONCE into
// global Wp (48 KB, L2-resident, shared by all QKV blocks).
__global__ void prep_kernel(int* __restrict__ gtail, int nb,
                            const float* __restrict__ Wq,
                            const float* __restrict__ Wk,
                            const float* __restrict__ Wv,
                            uint4* __restrict__ Wp) {
    int t = threadIdx.x;
    if (blockIdx.x == 0) {
        for (int i = t; i < nb; i += 256) gtail[i] = 0;
        return;
    }
    int c = (int)(blockIdx.x - 1) * 256 + t;  // 0..3071
    int s = c >> 9;
    int tt = (c >> 6) & 7;
    int L = c & 63;
    const float* wm = (s < 2) ? Wq : (s < 4) ? Wk : Wv;
    const float* wsrc = wm + (size_t)(tt * 32 + (L >> 4) * 8) * HS + (s & 1) * 16 + (L & 15);
    unsigned e0 = f2bf(wsrc[0 * HS]) | ((unsigned)f2bf(wsrc[1 * HS]) << 16);
    unsigned e1 = f2bf(wsrc[2 * HS]) | ((unsigned)f2bf(wsrc[3 * HS]) << 16);
    unsigned e2 = f2bf(wsrc[4 * HS]) | ((unsigned)f2bf(wsrc[5 * HS]) << 16);
    unsigned e3 = f2bf(wsrc[6 * HS]) | ((unsigned)f2bf(wsrc[7 * HS]) << 16);
    Wp[c] = make_uint4(e0, e1, e2, e3);
}

// R13 mega kernel: grid-fused {S1 edge partition} || {QKV MFMA proj}.
// R5 counters showed mega=71us ~= 1.6M scattered 8-B staging stores, each
// opening a random 64-B line (runs were 2.6 recs = 21 B): ~102 MB of
// line-granular random writes at ~1.5 TB/s. Fix: EPB=16384 (runs = 21
// recs, single-writer lines that accumulate in the local L2) + 4-B packed
// records ((src&127)<<17 | dst; halves payload and S2's read).
__global__ __launch_bounds__(256) void mega_kernel(
        const float* __restrict__ X, const uint4* __restrict__ Wp,
        const int* __restrict__ src, const int* __restrict__ dst,
        float* __restrict__ Q, unsigned short* __restrict__ KVb,
        int* __restrict__ gtail, unsigned* __restrict__ staging,
        int N, int E, int nb, int s1blocks, int ilv) {
    __shared__ int sh[NBUCK_MAX];   // per-block bucket histogram
    __shared__ int sbs[NBUCK_MAX];  // this block's base within each bucket
    __shared__ int srk[NBUCK_MAX];  // running rank (pass 2)
    int tid = threadIdx.x;
    int idx = (int)blockIdx.x;
    bool is_s1 = (idx % ilv == 0) && (idx / ilv < s1blocks);

    if (is_s1) {
        // ---- S1: two-pass bucket partition (pass 2 re-reads edges, L2-hot;
        // 64 edges/thread is too many for register stash) ----
        int e0 = (idx / ilv) * EPB;
        int lim = min(EPB, E - e0);
        for (int i = tid; i < nb; i += 256) { sh[i] = 0; srk[i] = 0; }
        __syncthreads();
        for (int i = tid; i < lim; i += 256)
            atomicAdd(&sh[src[e0 + i] >> BKT_SHIFT], 1);
        __syncthreads();
        // reserve global ranges: one device atomic per (block, nonzero bucket)
        for (int b = tid; b < nb; b += 256) {
            int c = sh[b];
            sbs[b] = c ? atomicAdd(&gtail[b], c) : 0;
        }
        __syncthreads();
        // scatter packed records into bucket staging (fire-and-forget;
        // this block's ~21-rec runs accumulate full lines in local L2)
        for (int i = tid; i < lim; i += 256) {
            int s = src[e0 + i];
            unsigned d = (unsigned)dst[e0 + i];
            int b = s >> BKT_SHIFT;
            int r = atomicAdd(&srk[b], 1);
            int pos = sbs[b] + r;
            if (pos < CAP)  // +11 sigma; OOB guard only
                staging[(size_t)b * CAP + pos] =
                    ((unsigned)(s & (BKT_NODES - 1)) << 17) | d;
        }
        return;
    }

    // ---- QKV projection (MFMA), LDS-free. Q fp32; K,V bf16 interleaved
    // per node: 128-B row of 8 chunks { K[c*4..+3], V[c*4..+3] } so the
    // gather pass fetches K and V with ONE dwordx4 per lane. ----
    int bq = idx - min(idx / ilv + 1, s1blocks);
    int wave = tid >> 6;
    int L = tid & 63;
    int quad = L >> 4;
    int lane16 = L & 15;
    int mt = bq * 4 + wave;
    if (mt * 16 >= N) return;

    const float* xrow = X + (size_t)(mt * 16 + lane16) * N_INPUT + quad * 8;
    bf16x8 afrag[8];
#pragma unroll
    for (int t = 0; t < 8; ++t) {
        float4 a0 = *(const float4*)(xrow + t * 32);
        float4 a1 = *(const float4*)(xrow + t * 32 + 4);
        bf16x8 f;
        f[0] = (short)f2bf(a0.x); f[1] = (short)f2bf(a0.y);
        f[2] = (short)f2bf(a0.z); f[3] = (short)f2bf(a0.w);
        f[4] = (short)f2bf(a1.x); f[5] = (short)f2bf(a1.y);
        f[6] = (short)f2bf(a1.z); f[7] = (short)f2bf(a1.w);
        afrag[t] = f;
    }

#pragma unroll
    for (int s = 0; s < 6; ++s) {
        f32x4 acc = {0.f, 0.f, 0.f, 0.f};
#pragma unroll
        for (int t = 0; t < 8; ++t) {
            bf16x8 bfrag = ((const bf16x8*)Wp)[(s * 8 + t) * 64 + L];
            acc = __builtin_amdgcn_mfma_f32_16x16x32_bf16(afrag[t], bfrag, acc, 0, 0, 0);
        }
        int col = (s & 1) * 16 + lane16;
#pragma unroll
        for (int r = 0; r < 4; ++r) {
            int row = mt * 16 + quad * 4 + r;
            if (s < 2) {
                Q[(size_t)row * HS + col] = acc[r];
            } else {
                size_t pos = (size_t)row * 64 + (size_t)(col >> 2) * 8 +
                             ((s < 4) ? 0 : 4) + (col & 3);
                KVb[pos] = f2bf(acc[r]);
            }
        }
    }
}

// R10 fused S2+aggregation: one block per 128-node bucket. Builds the
// per-node edge lists ENTIRELY IN LDS, then the same block's 16 32-lane
// groups aggregate its nodes straight from LDS. R13: staging records are
// 4-B packed (sl<<17 | dst).
__global__ __launch_bounds__(512) void s2_agg_kernel(
        const unsigned* __restrict__ staging, const int* __restrict__ gtail,
        const float* __restrict__ Q, const unsigned short* __restrict__ KVb,
        float* __restrict__ out, int N) {
    __shared__ int ldst[CAP];        // 10 KB sorted dst list
    __shared__ int nh[BKT_NODES];    // per-node count
    __shared__ int nx[BKT_NODES];    // inclusive scan
    __shared__ int rk[BKT_NODES];    // rank
    int b = blockIdx.x;
    int t = threadIdx.x;
    int cnt = min(gtail[b], CAP);
    if (t < BKT_NODES) { nh[t] = 0; rk[t] = 0; }
    __syncthreads();
    // hist pass; stash records in regs (static idx - rule #20)
    unsigned stash[5];
#pragma unroll
    for (int k = 0; k < 5; ++k) {
        int i = t + k * 512;
        if (i < cnt) {
            unsigned e = staging[(size_t)b * CAP + i];
            stash[k] = e;
            atomicAdd(&nh[e >> 17], 1);
        }
    }
    __syncthreads();
    if (t < BKT_NODES) nx[t] = nh[t];
    __syncthreads();
    for (int off = 1; off < BKT_NODES; off <<= 1) {
        int u = (t >= off && t < BKT_NODES) ? nx[t - off] : 0;
        __syncthreads();
        if (t < BKT_NODES) nx[t] += u;
        __syncthreads();
    }
#pragma unroll
    for (int k = 0; k < 5; ++k) {
        int i = t + k * 512;
        if (i < cnt) {
            unsigned e = stash[k];
            int sl = (int)(e >> 17);
            int r = atomicAdd(&rk[sl], 1);  // LDS atomic
            ldst[nx[sl] - nh[sl] + r] = (int)(e & 0x1FFFFu);
        }
    }
    __syncthreads();

    // ---- aggregation: 16 groups of 32 lanes; 4 edge slots x 8 sub-lanes ----
    int lane = t & 31;
    int grp = t >> 5;
    int slot = lane >> 3;
    int sub = lane & 7;
    int node0 = b << BKT_SHIFT;
    for (int ni = grp; ni < BKT_NODES; ni += 16) {
        int n = node0 + ni;
        if (n >= N) continue;
        int end = nx[ni];
        int beg = end - nh[ni];
        float4 qf = *(const float4*)(Q + (size_t)n * HS + sub * 4);
        float4 acc = make_float4(0.f, 0.f, 0.f, 0.f);
        float den = 0.f;
        for (int j = beg; j < end; j += 4) {
            int e = j + slot;
            bool valid = e < end;
            int d = valid ? ldst[e] : 0;  // LDS broadcast (8 lanes same addr)
            u16x8 kv = *(const u16x8*)(KVb + (size_t)d * 64 + sub * 8);
            float p = qf.x * bf2f(kv[0]) + qf.y * bf2f(kv[1]) +
                      qf.z * bf2f(kv[2]) + qf.w * bf2f(kv[3]);
            p += __shfl_xor(p, 1, 32);
            p += __shfl_xor(p, 2, 32);
            p += __shfl_xor(p, 4, 32);
            float ex = valid ? __expf(p * 0.17677669529663687f) : 0.f;  // 1/sqrt(32)
            den += ex;
            acc.x += ex * bf2f(kv[4]);
            acc.y += ex * bf2f(kv[5]);
            acc.z += ex * bf2f(kv[6]);
            acc.w += ex * bf2f(kv[7]);
        }
        // sum the 4 edge slots (xor over slot bits 3,4)
#pragma unroll
        for (int off = 8; off <= 16; off <<= 1) {
            acc.x += __shfl_xor(acc.x, off, 32);
            acc.y += __shfl_xor(acc.y, off, 32);
            acc.z += __shfl_xor(acc.z, off, 32);
            acc.w += __shfl_xor(acc.w, off, 32);
            den += __shfl_xor(den, off, 32);
        }
        if (lane < 8) {
            float4 o = make_float4(0.f, 0.f, 0.f, 0.f);
            if (end > beg) {
                float rd = 1.f / den;
                o = make_float4(acc.x * rd, acc.y * rd, acc.z * rd, acc.w * rd);
            }
            *(float4*)(out + (size_t)n * HS + lane * 4) = o;
        }
    }
}

extern "C" void kernel_launch(void* const* d_in, const int* in_sizes, int n_in,
                              void* d_out, int out_size, void* d_ws, size_t ws_size,
                              hipStream_t stream) {
    const float* X  = (const float*)d_in[0];
    const int*   ei = (const int*)d_in[1];
    const float* Wq = (const float*)d_in[2];
    const float* Wk = (const float*)d_in[3];
    const float* Wv = (const float*)d_in[4];

    int N = in_sizes[0] / N_INPUT;
    int E = in_sizes[1] / 2;
    const int* src = ei;
    const int* dst = ei + E;

    // ws layout: Q[N*32] fp32 (12.8 MB); KVb[N*64] bf16 interleaved rows
    // (12.8 MB); Wp[3072] uint4 (48 KB); gtail[NBUCK_MAX];
    // staging[nbuck*CAP] 4-B packed records (8 MB). No aliasing.
    float* ws = (float*)d_ws;
    float* Q = ws;
    unsigned short* KVb = (unsigned short*)(Q + (size_t)N * HS);
    uint4* Wp = (uint4*)(KVb + (size_t)N * 64);
    int* gtail = (int*)(Wp + 3072);
    unsigned* staging = (unsigned*)(gtail + NBUCK_MAX);
    float* out = (float*)d_out;

    int nbuck = (N + BKT_NODES - 1) >> BKT_SHIFT;  // 782
    int s1blocks = (E + EPB - 1) / EPB;            // 98
    int mtiles = (N + 15) / 16;
    int qblocks = (mtiles + 3) / 4;                // 1563
    int total = s1blocks + qblocks;                // 1661
    int ilv = total / s1blocks;                    // 16
    if (ilv < 1) ilv = 1;

    prep_kernel<<<13, 256, 0, stream>>>(gtail, nbuck, Wq, Wk, Wv, Wp);
    mega_kernel<<<total, 256, 0, stream>>>(
        X, Wp, src, dst, Q, KVb, gtail, staging, N, E, nbuck, s1blocks, ilv);
    s2_agg_kernel<<<nbuck, 512, 0, stream>>>(staging, gtail, Q, KVb, out, N);
}

// Round 7
// 229.278 us; speedup vs baseline: 2.0620x; 2.0620x over previous
//
#include <hip/hip_runtime.h>

#define N_INPUT 256
#define HS 32

// ---- bucket-sort CSR build params ----
#define BKT_SHIFT 7
#define BKT_NODES 128           // nodes per bucket
#define NBUCK_MAX 800           // LDS sizing; runtime nbuck = ceil(N/128) = 782
#define CAP 2560                // per-bucket edge capacity (mean 2048, sigma ~45 -> +11 sigma)
#define EPB 2048                // edges per S1 block (R14: REVERTED to R12. R13's
                                // EPB=16384 cut S1 to 98 blocks = 1.5 waves/CU ->
                                // 315us straggler tail, occupancy 5.7%. Granularity
                                // must stay fine; parallelism beats line-merging.)

typedef __attribute__((ext_vector_type(8))) short bf16x8;
typedef __attribute__((ext_vector_type(4))) float f32x4;
typedef __attribute__((ext_vector_type(8))) unsigned short u16x8;

// fp32 -> bf16 bits, round-to-nearest-even
__device__ __forceinline__ unsigned short f2bf(float f) {
    unsigned u = __float_as_uint(f);
    unsigned r = u + 0x7FFFu + ((u >> 16) & 1u);
    return (unsigned short)(r >> 16);
}
__device__ __forceinline__ float bf2f(unsigned short u) {
    return __uint_as_float((unsigned)u << 16);
}

// R12 prep: zero gtail + pack the frag-ordered bf16 weights ONCE into
// global Wp (48 KB, L2-resident, shared by all QKV blocks).
__global__ void prep_kernel(int* __restrict__ gtail, int nb,
                            const float* __restrict__ Wq,
                            const float* __restrict__ Wk,
                            const float* __restrict__ Wv,
                            uint4* __restrict__ Wp) {
    int t = threadIdx.x;
    if (blockIdx.x == 0) {
        for (int i = t; i < nb; i += 256) gtail[i] = 0;
        return;
    }
    int c = (int)(blockIdx.x - 1) * 256 + t;  // 0..3071
    int s = c >> 9;
    int tt = (c >> 6) & 7;
    int L = c & 63;
    const float* wm = (s < 2) ? Wq : (s < 4) ? Wk : Wv;
    const float* wsrc = wm + (size_t)(tt * 32 + (L >> 4) * 8) * HS + (s & 1) * 16 + (L & 15);
    unsigned e0 = f2bf(wsrc[0 * HS]) | ((unsigned)f2bf(wsrc[1 * HS]) << 16);
    unsigned e1 = f2bf(wsrc[2 * HS]) | ((unsigned)f2bf(wsrc[3 * HS]) << 16);
    unsigned e2 = f2bf(wsrc[4 * HS]) | ((unsigned)f2bf(wsrc[5 * HS]) << 16);
    unsigned e3 = f2bf(wsrc[6 * HS]) | ((unsigned)f2bf(wsrc[7 * HS]) << 16);
    Wp[c] = make_uint4(e0, e1, e2, e3);
}

// R14 mega kernel: grid-fused {S1 edge partition} || {QKV MFMA proj} --
// exact R12 structure (EPB=2048, 782 S1 blocks, %3 interleave; measured
// 71.5us) with R13's one safe piece kept: 4-B packed staging records
// ((src&127)<<17 | dst) halve scatter payload and S2's staging read.
__global__ __launch_bounds__(256) void mega_kernel(
        const float* __restrict__ X, const uint4* __restrict__ Wp,
        const int* __restrict__ src, const int* __restrict__ dst,
        float* __restrict__ Q, unsigned short* __restrict__ KVb,
        int* __restrict__ gtail, unsigned* __restrict__ staging,
        int N, int E, int nb, int s1blocks) {
    __shared__ int sh[NBUCK_MAX];   // per-block bucket histogram
    __shared__ int sbs[NBUCK_MAX];  // this block's base within each bucket
    int tid = threadIdx.x;
    int idx = (int)blockIdx.x;
    bool is_s1 = (idx % 3 == 0) && (idx / 3 < s1blocks);

    if (is_s1) {
        // ---- S1: single-pass bucket partition (rank cached in registers) ----
        int e0 = (idx / 3) * EPB;
        for (int i = tid; i < nb; i += 256) sh[i] = 0;
        __syncthreads();
        int ss[8], dd[8], rr[8];
#pragma unroll
        for (int k = 0; k < 8; ++k) {
            int i = e0 + tid + k * 256;
            ss[k] = -1;
            if (i < E) {
                int s = src[i];
                dd[k] = dst[i];
                ss[k] = s;
                rr[k] = atomicAdd(&sh[s >> BKT_SHIFT], 1);
            }
        }
        __syncthreads();
        // reserve global ranges: one device atomic per (block, nonzero bucket)
        for (int b = tid; b < nb; b += 256) {
            int c = sh[b];
            sbs[b] = c ? atomicAdd(&gtail[b], c) : 0;
        }
        __syncthreads();
        // scatter 4-B packed records into bucket staging (fire-and-forget)
#pragma unroll
        for (int k = 0; k < 8; ++k) {
            if (ss[k] >= 0) {
                int b = ss[k] >> BKT_SHIFT;
                int pos = sbs[b] + rr[k];
                if (pos < CAP)  // +11 sigma; OOB guard only
                    staging[(size_t)b * CAP + pos] =
                        ((unsigned)(ss[k] & (BKT_NODES - 1)) << 17) | (unsigned)dd[k];
            }
        }
        return;
    }

    // ---- QKV projection (MFMA), LDS-free. Q fp32; K,V bf16 interleaved
    // per node: 128-B row of 8 chunks { K[c*4..+3], V[c*4..+3] } so the
    // gather pass fetches K and V with ONE dwordx4 per lane. ----
    int bq = idx - min(idx / 3 + 1, s1blocks);
    int wave = tid >> 6;
    int L = tid & 63;
    int quad = L >> 4;
    int lane16 = L & 15;
    int mt = bq * 4 + wave;
    if (mt * 16 >= N) return;

    const float* xrow = X + (size_t)(mt * 16 + lane16) * N_INPUT + quad * 8;
    bf16x8 afrag[8];
#pragma unroll
    for (int t = 0; t < 8; ++t) {
        float4 a0 = *(const float4*)(xrow + t * 32);
        float4 a1 = *(const float4*)(xrow + t * 32 + 4);
        bf16x8 f;
        f[0] = (short)f2bf(a0.x); f[1] = (short)f2bf(a0.y);
        f[2] = (short)f2bf(a0.z); f[3] = (short)f2bf(a0.w);
        f[4] = (short)f2bf(a1.x); f[5] = (short)f2bf(a1.y);
        f[6] = (short)f2bf(a1.z); f[7] = (short)f2bf(a1.w);
        afrag[t] = f;
    }

#pragma unroll
    for (int s = 0; s < 6; ++s) {
        f32x4 acc = {0.f, 0.f, 0.f, 0.f};
#pragma unroll
        for (int t = 0; t < 8; ++t) {
            bf16x8 bfrag = ((const bf16x8*)Wp)[(s * 8 + t) * 64 + L];
            acc = __builtin_amdgcn_mfma_f32_16x16x32_bf16(afrag[t], bfrag, acc, 0, 0, 0);
        }
        int col = (s & 1) * 16 + lane16;
#pragma unroll
        for (int r = 0; r < 4; ++r) {
            int row = mt * 16 + quad * 4 + r;
            if (s < 2) {
                Q[(size_t)row * HS + col] = acc[r];
            } else {
                size_t pos = (size_t)row * 64 + (size_t)(col >> 2) * 8 +
                             ((s < 4) ? 0 : 4) + (col & 3);
                KVb[pos] = f2bf(acc[r]);
            }
        }
    }
}

// R10 fused S2+aggregation: one block per 128-node bucket. Builds the
// per-node edge lists ENTIRELY IN LDS, then the same block's 16 32-lane
// groups aggregate its nodes straight from LDS. R14: 1-deep software
// pipeline on the KV gather -- issue iteration j+1's ldst lookup + 128-B
// KVb gather BEFORE computing iteration j (KVb is 12.8 MB > 4 MB per-XCD
// L2, so gathers are ~L3 latency; the shuffle/exp chain now overlaps it).
__global__ __launch_bounds__(512) void s2_agg_kernel(
        const unsigned* __restrict__ staging, const int* __restrict__ gtail,
        const float* __restrict__ Q, const unsigned short* __restrict__ KVb,
        float* __restrict__ out, int N) {
    __shared__ int ldst[CAP];        // 10 KB sorted dst list
    __shared__ int nh[BKT_NODES];    // per-node count
    __shared__ int nx[BKT_NODES];    // inclusive scan
    __shared__ int rk[BKT_NODES];    // rank
    int b = blockIdx.x;
    int t = threadIdx.x;
    int cnt = min(gtail[b], CAP);
    if (t < BKT_NODES) { nh[t] = 0; rk[t] = 0; }
    __syncthreads();
    // hist pass; stash records in regs (static idx - rule #20)
    unsigned stash[5];
#pragma unroll
    for (int k = 0; k < 5; ++k) {
        int i = t + k * 512;
        if (i < cnt) {
            unsigned e = staging[(size_t)b * CAP + i];
            stash[k] = e;
            atomicAdd(&nh[e >> 17], 1);
        }
    }
    __syncthreads();
    if (t < BKT_NODES) nx[t] = nh[t];
    __syncthreads();
    for (int off = 1; off < BKT_NODES; off <<= 1) {
        int u = (t >= off && t < BKT_NODES) ? nx[t - off] : 0;
        __syncthreads();
        if (t < BKT_NODES) nx[t] += u;
        __syncthreads();
    }
#pragma unroll
    for (int k = 0; k < 5; ++k) {
        int i = t + k * 512;
        if (i < cnt) {
            unsigned e = stash[k];
            int sl = (int)(e >> 17);
            int r = atomicAdd(&rk[sl], 1);  // LDS atomic
            ldst[nx[sl] - nh[sl] + r] = (int)(e & 0x1FFFFu);
        }
    }
    __syncthreads();

    // ---- aggregation: 16 groups of 32 lanes; 4 edge slots x 8 sub-lanes ----
    int lane = t & 31;
    int grp = t >> 5;
    int slot = lane >> 3;
    int sub = lane & 7;
    int node0 = b << BKT_SHIFT;
    for (int ni = grp; ni < BKT_NODES; ni += 16) {
        int n = node0 + ni;
        if (n >= N) continue;
        int end = nx[ni];
        int beg = end - nh[ni];
        float4 qf = *(const float4*)(Q + (size_t)n * HS + sub * 4);
        float4 acc = make_float4(0.f, 0.f, 0.f, 0.f);
        float den = 0.f;
        // 1-deep pipelined edge loop: gather for j+4 issued before compute of j
        int d0 = (beg + slot < end) ? ldst[beg + slot] : 0;
        u16x8 kvc = *(const u16x8*)(KVb + (size_t)d0 * 64 + sub * 8);
        for (int j = beg; j < end; j += 4) {
            bool valid = (j + slot) < end;
            u16x8 kv = kvc;
            int jn = j + 4;
            if (jn < end) {  // group-uniform branch
                int dn = (jn + slot < end) ? ldst[jn + slot] : 0;
                kvc = *(const u16x8*)(KVb + (size_t)dn * 64 + sub * 8);
            }
            float p = qf.x * bf2f(kv[0]) + qf.y * bf2f(kv[1]) +
                      qf.z * bf2f(kv[2]) + qf.w * bf2f(kv[3]);
            p += __shfl_xor(p, 1, 32);
            p += __shfl_xor(p, 2, 32);
            p += __shfl_xor(p, 4, 32);
            float ex = valid ? __expf(p * 0.17677669529663687f) : 0.f;  // 1/sqrt(32)
            den += ex;
            acc.x += ex * bf2f(kv[4]);
            acc.y += ex * bf2f(kv[5]);
            acc.z += ex * bf2f(kv[6]);
            acc.w += ex * bf2f(kv[7]);
        }
        // sum the 4 edge slots (xor over slot bits 3,4)
#pragma unroll
        for (int off = 8; off <= 16; off <<= 1) {
            acc.x += __shfl_xor(acc.x, off, 32);
            acc.y += __shfl_xor(acc.y, off, 32);
            acc.z += __shfl_xor(acc.z, off, 32);
            acc.w += __shfl_xor(acc.w, off, 32);
            den += __shfl_xor(den, off, 32);
        }
        if (lane < 8) {
            float4 o = make_float4(0.f, 0.f, 0.f, 0.f);
            if (end > beg) {
                float rd = 1.f / den;
                o = make_float4(acc.x * rd, acc.y * rd, acc.z * rd, acc.w * rd);
            }
            *(float4*)(out + (size_t)n * HS + lane * 4) = o;
        }
    }
}

extern "C" void kernel_launch(void* const* d_in, const int* in_sizes, int n_in,
                              void* d_out, int out_size, void* d_ws, size_t ws_size,
                              hipStream_t stream) {
    const float* X  = (const float*)d_in[0];
    const int*   ei = (const int*)d_in[1];
    const float* Wq = (const float*)d_in[2];
    const float* Wk = (const float*)d_in[3];
    const float* Wv = (const float*)d_in[4];

    int N = in_sizes[0] / N_INPUT;
    int E = in_sizes[1] / 2;
    const int* src = ei;
    const int* dst = ei + E;

    // ws layout: Q[N*32] fp32 (12.8 MB); KVb[N*64] bf16 interleaved rows
    // (12.8 MB); Wp[3072] uint4 (48 KB); gtail[NBUCK_MAX];
    // staging[nbuck*CAP] 4-B packed records (8 MB). No aliasing.
    float* ws = (float*)d_ws;
    float* Q = ws;
    unsigned short* KVb = (unsigned short*)(Q + (size_t)N * HS);
    uint4* Wp = (uint4*)(KVb + (size_t)N * 64);
    int* gtail = (int*)(Wp + 3072);
    unsigned* staging = (unsigned*)(gtail + NBUCK_MAX);
    float* out = (float*)d_out;

    int nbuck = (N + BKT_NODES - 1) >> BKT_SHIFT;  // 782
    int s1blocks = (E + EPB - 1) / EPB;            // 782
    int mtiles = (N + 15) / 16;
    int qblocks = (mtiles + 3) / 4;                // 1563

    prep_kernel<<<13, 256, 0, stream>>>(gtail, nbuck, Wq, Wk, Wv, Wp);
    mega_kernel<<<s1blocks + qblocks, 256, 0, stream>>>(
        X, Wp, src, dst, Q, KVb, gtail, staging, N, E, nbuck, s1blocks);
    s2_agg_kernel<<<nbuck, 512, 0, stream>>>(staging, gtail, Q, KVb, out, N);
}